// Round 16
// baseline (72.515 us; speedup 1.0000x reference)
//
#include <hip/hip_runtime.h>
#include <math.h>

#define NB 16
#define DIN 512
#define TT 4096
#define DCB 8
#define KC 1024
#define NW 8

typedef float v2f __attribute__((ext_vector_type(2)));

// v_pk_*_f32 with op_sel word-broadcast of src1 (wave-uniform cb operand).
#define PK_MUL_HI(d, a, b)    asm("v_pk_mul_f32 %0, %1, %2 op_sel:[0,1]"          : "=v"(d) : "v"(a), "v"(b))
#define PK_FMA_LO(d, a, b, c) asm("v_pk_fma_f32 %0, %1, %2, %3 op_sel_hi:[1,0,1]" : "=v"(d) : "v"(a), "v"(b), "v"(c))
#define PK_FMA_HI(d, a, b, c) asm("v_pk_fma_f32 %0, %1, %2, %3 op_sel:[0,1,0]"    : "=v"(d) : "v"(a), "v"(b), "v"(c))
#define PK_FMA(d, a, b, c)    asm("v_pk_fma_f32 %0, %1, %2, %3"                   : "=v"(d) : "v"(a), "v"(b), "v"(c))
#define PK_ADD_LO(d, a, b)    asm("v_pk_add_f32 %0, %1, %2 op_sel_hi:[1,0]"       : "=v"(d) : "v"(a), "v"(b))
#define PK_ADD_HI(d, a, b)    asm("v_pk_add_f32 %0, %1, %2 op_sel:[0,1]"          : "=v"(d) : "v"(a), "v"(b))

// ws layout (floats):
// [0,4096)      w_inT[d][c]
// [4096,8192)   w_out[o][c]
// [8192,9216)   cb2[k]
// [9216,9728)   per-block commit partials (512)

__global__ __launch_bounds__(512) void vq_setup(
    const float* __restrict__ in_v, const float* __restrict__ in_g,
    const float* __restrict__ out_v, const float* __restrict__ out_g,
    const float* __restrict__ cb, float* __restrict__ ws)
{
    int tid = threadIdx.x;
    float* w_inT = ws;
    float* w_out = ws + 4096;
    float* cb2   = ws + 8192;

    {   // w_in: 8 rows of 512; one wave per row
        int c    = tid >> 6;
        int lane = tid & 63;
        const float* v = in_v + c * DIN;
        float s = 0.f;
        #pragma unroll
        for (int i = 0; i < DIN; i += 64) {
            float x = v[i + lane];
            s += x * x;
        }
        #pragma unroll
        for (int off = 32; off > 0; off >>= 1) s += __shfl_xor(s, off, 64);
        float sq = sqrtf(s);
        float g  = in_g[c];
        #pragma unroll
        for (int i = 0; i < DIN; i += 64) {
            int d = i + lane;
            w_inT[d * DCB + c] = (g * v[d]) / sq;
        }
    }
    {   // w_out: 512 rows of 8
        int o = tid;
        const float* v = out_v + o * DCB;
        float s = 0.f;
        #pragma unroll
        for (int c = 0; c < DCB; ++c) s += v[c] * v[c];
        float sq = sqrtf(s);
        float g  = out_g[o];
        #pragma unroll
        for (int c = 0; c < DCB; ++c) w_out[o * DCB + c] = (g * v[c]) / sq;
    }
    for (int k = tid; k < KC; k += 512) {
        const float* r = cb + k * DCB;
        float s = 0.f;
        #pragma unroll
        for (int c = 0; c < DCB; ++c) s += r[c] * r[c];
        cb2[k] = s;
    }
}

// One packed scan step over k, k+1 for a t-pair (r14-verified, bit-exact chain).
__device__ __forceinline__ void scan2(const float* s_cb, const float* s_cb2,
    int kbase, const v2f* zt, v2f enc2p,
    float& best0, float& best1, int& bi0, int& bi1)
{
    v2f c2q = *(const v2f*)(s_cb2 + kbase);
    #pragma unroll
    for (int u = 0; u < 2; ++u) {
        int k = kbase + u;
        float4 r0 = ((const float4*)s_cb)[2 * k];
        float4 r1 = ((const float4*)s_cb)[2 * k + 1];
        v2f cbA = (v2f){r0.x, r0.y};
        v2f cbB = (v2f){r0.z, r0.w};
        v2f cbC = (v2f){r1.x, r1.y};
        v2f cbD = (v2f){r1.z, r1.w};
        v2f acc;
        PK_MUL_HI(acc, zt[7], cbD);
        PK_FMA_LO(acc, zt[6], cbD, acc);
        PK_FMA_HI(acc, zt[5], cbC, acc);
        PK_FMA_LO(acc, zt[4], cbC, acc);
        PK_FMA_HI(acc, zt[3], cbB, acc);
        PK_FMA_LO(acc, zt[2], cbB, acc);
        PK_FMA_HI(acc, zt[1], cbA, acc);
        PK_FMA_LO(acc, zt[0], cbA, acc);
        v2f neg2 = (v2f){-2.0f, -2.0f};
        v2f dk2;
        PK_FMA(dk2, acc, neg2, enc2p);
        if (u == 0) { PK_ADD_LO(dk2, dk2, c2q); }
        else        { PK_ADD_HI(dk2, dk2, c2q); }
        if (dk2.x < best0) { best0 = dk2.x; bi0 = k; }
        if (dk2.y < best1) { best1 = dk2.y; bi1 = k; }
    }
}

// Pipelined fused main. 512 blocks x 512 threads; block = (b, 128-t chunk).
// Sub-chunks A = [t0,t0+64), B = [t0+64,t0+128); lane owns one t per sub-chunk.
// Pipeline: inA | redA | [inB loads ⊗ scanA] | redB+combineA | [outA ⊗ scanB]
//           | combineB | outB  — scans hide under memory issue/drain.
__global__ __launch_bounds__(512, 4) void vq_main(
    const float* __restrict__ z, const float* __restrict__ in_b,
    const float* __restrict__ out_b, const float* __restrict__ cb,
    const float* __restrict__ ws, float* __restrict__ ws_commit,
    float* __restrict__ out)
{
    __shared__ float s_cb[KC * DCB];   // 32 KB [k][c]
    __shared__ float s_cb2[KC];        // 4 KB
    __shared__ float s_red[NW * DCB * 64];  // 16 KB, reused A then B
    __shared__ float s_zeA[DCB * 64];  // 2 KB [c][t]
    __shared__ float s_zeB[DCB * 64];  // 2 KB
    __shared__ float s_sd[16][64];     // 4 KB, reused A then B
    __shared__ int   s_si[16][64];     // 4 KB   -> 64 KB total, 2 blocks/CU

    const float* w_inT = ws;
    const float* w_out = ws + 4096;

    int tid  = threadIdx.x;
    int w    = tid >> 6;
    int wu   = __builtin_amdgcn_readfirstlane(w);
    int lane = tid & 63;
    int blk  = blockIdx.x;               // 0..511
    int b    = blk >> 5;
    int t0   = (blk & 31) * 128;
    int d0   = wu * 64;

    // ---- stage cb + cb2 into LDS (short live range) ----
    {
        float4 c0 = ((const float4*)cb)[tid];
        float4 c1 = ((const float4*)cb)[512 + tid];
        float4 c2 = ((const float4*)cb)[1024 + tid];
        float4 c3 = ((const float4*)cb)[1536 + tid];
        ((float4*)s_cb)[tid]        = c0;
        ((float4*)s_cb)[512 + tid]  = c1;
        ((float4*)s_cb)[1024 + tid] = c2;
        ((float4*)s_cb)[1536 + tid] = c3;
        if (tid < 256) {
            float4 q = ((const float4*)(ws + 8192))[tid];
            ((float4*)s_cb2)[tid] = q;
        }
    }

    const float* zpA = z + (size_t)b * DIN * TT + t0 + lane;

    // ---- in-proj A: d in [d0,d0+64), lane owns t = t0+lane ----
    float zeA[DCB];
    #pragma unroll
    for (int c = 0; c < DCB; ++c) zeA[c] = 0.f;
    for (int db = 0; db < 64; db += 8) {
        float v[8];
        #pragma unroll
        for (int j = 0; j < 8; ++j) v[j] = zpA[(size_t)(d0 + db + j) * TT];
        #pragma unroll
        for (int j = 0; j < 8; ++j) {
            const float* wi = w_inT + (d0 + db + j) * DCB;   // uniform -> s_load
            #pragma unroll
            for (int c = 0; c < DCB; ++c) zeA[c] = fmaf(wi[c], v[j], zeA[c]);
        }
    }
    #pragma unroll
    for (int c = 0; c < DCB; ++c) s_red[w * 512 + c * 64 + lane] = zeA[c];
    __syncthreads();   // (1) redA + cb staged

    // ---- distributed reduce A: thread (w,lane) owns (c=w, t=lane) ----
    {
        float sa = 0.f;
        #pragma unroll
        for (int w2 = 0; w2 < NW; ++w2) sa += s_red[w2 * 512 + w * 64 + lane];
        s_zeA[w * 64 + lane] = sa + in_b[w];
    }
    __syncthreads();   // (2) zeA visible, red reusable

    // ---- scan state for A: lane covers t-pair t2,t2+1; slice s = 2w+h ----
    int h    = lane >> 5;
    int t2   = 2 * (lane & 31);
    int sidx = 2 * w + h;
    int k0   = 64 * sidx;

    v2f zA[DCB];
    #pragma unroll
    for (int c = 0; c < DCB; ++c) zA[c] = *(const v2f*)(s_zeA + c * 64 + t2);
    v2f enc2pA;
    {
        float e0 = 0.f, e1 = 0.f;
        #pragma unroll
        for (int c = 0; c < DCB; ++c) { e0 += zA[c].x * zA[c].x; e1 += zA[c].y * zA[c].y; }
        enc2pA = (v2f){e0, e1};
    }
    float bestA0 = 3.4e38f, bestA1 = 3.4e38f;
    int   biA0 = 0, biA1 = 0;

    // ---- MIXED 1: in-proj B loads  ⊗  scan A ----
    const float* zpB = zpA + 64;
    float zeB[DCB];
    #pragma unroll
    for (int c = 0; c < DCB; ++c) zeB[c] = 0.f;
    for (int it = 0; it < 8; ++it) {
        float v[8];
        #pragma unroll
        for (int j = 0; j < 8; ++j)
            v[j] = zpB[(size_t)(d0 + it * 8 + j) * TT];      // loads in flight
        #pragma unroll
        for (int kk = 0; kk < 8; kk += 2)                    // scanA hides here
            scan2(s_cb, s_cb2, k0 + it * 8 + kk, zA, enc2pA, bestA0, bestA1, biA0, biA1);
        #pragma unroll
        for (int j = 0; j < 8; ++j) {
            const float* wi = w_inT + (d0 + it * 8 + j) * DCB;
            #pragma unroll
            for (int c = 0; c < DCB; ++c) zeB[c] = fmaf(wi[c], v[j], zeB[c]);
        }
    }
    #pragma unroll
    for (int c = 0; c < DCB; ++c) s_red[w * 512 + c * 64 + lane] = zeB[c];
    *(float2*)(&s_sd[sidx][t2]) = make_float2(bestA0, bestA1);
    *(int2*)  (&s_si[sidx][t2]) = make_int2(biA0, biA1);
    __syncthreads();   // (3) redB + sdA/siA visible

    // ---- combine A (t=lane), ordered s ascending, strict < ----
    int gbiA;
    {
        float g = s_sd[0][lane];
        gbiA = s_si[0][lane];
        #pragma unroll
        for (int s2 = 1; s2 < 16; ++s2) {
            float d2 = s_sd[s2][lane];
            int   i2 = s_si[s2][lane];
            if (d2 < g) { g = d2; gbiA = i2; }
        }
    }
    float4 qAa = ((const float4*)s_cb)[2 * gbiA];
    float4 qAb = ((const float4*)s_cb)[2 * gbiA + 1];

    // ---- distributed reduce B ----
    {
        float sa = 0.f;
        #pragma unroll
        for (int w2 = 0; w2 < NW; ++w2) sa += s_red[w2 * 512 + w * 64 + lane];
        s_zeB[w * 64 + lane] = sa + in_b[w];
    }
    __syncthreads();   // (4) zeB visible; sd/si reusable

    // ---- commit A + idx A (wave 0) ----
    float clA = 0.f;
    if (wu == 0) {
        float f;
        f = s_zeA[0*64+lane]-qAa.x; clA = fmaf(f,f,clA);
        f = s_zeA[1*64+lane]-qAa.y; clA = fmaf(f,f,clA);
        f = s_zeA[2*64+lane]-qAa.z; clA = fmaf(f,f,clA);
        f = s_zeA[3*64+lane]-qAa.w; clA = fmaf(f,f,clA);
        f = s_zeA[4*64+lane]-qAb.x; clA = fmaf(f,f,clA);
        f = s_zeA[5*64+lane]-qAb.y; clA = fmaf(f,f,clA);
        f = s_zeA[6*64+lane]-qAb.z; clA = fmaf(f,f,clA);
        f = s_zeA[7*64+lane]-qAb.w; clA = fmaf(f,f,clA);
        #pragma unroll
        for (int off = 32; off > 0; off >>= 1) clA += __shfl_xor(clA, off, 64);
        out[(size_t)NB * DIN * TT + NB + (size_t)b * TT + t0 + lane] = (float)gbiA;
    }

    // ---- scan state for B ----
    v2f zB[DCB];
    #pragma unroll
    for (int c = 0; c < DCB; ++c) zB[c] = *(const v2f*)(s_zeB + c * 64 + t2);
    v2f enc2pB;
    {
        float e0 = 0.f, e1 = 0.f;
        #pragma unroll
        for (int c = 0; c < DCB; ++c) { e0 += zB[c].x * zB[c].x; e1 += zB[c].y * zB[c].y; }
        enc2pB = (v2f){e0, e1};
    }
    float bestB0 = 3.4e38f, bestB1 = 3.4e38f;
    int   biB0 = 0, biB1 = 0;

    // ---- MIXED 2: out-proj A stores  ⊗  scan B ----
    float* outpA = out + (size_t)b * DIN * TT + t0 + lane;
    for (int it = 0; it < 8; ++it) {
        #pragma unroll
        for (int j = 0; j < 8; ++j) {
            int o = d0 + it * 8 + j;
            const float* wo = w_out + o * DCB;   // uniform -> s_load
            float a = fmaf(wo[0], qAa.x, fmaf(wo[1], qAa.y, fmaf(wo[2], qAa.z, fmaf(wo[3], qAa.w,
                      fmaf(wo[4], qAb.x, fmaf(wo[5], qAb.y, fmaf(wo[6], qAb.z, wo[7] * qAb.w)))))));
            outpA[(size_t)o * TT] = a + out_b[o];   // fire-and-forget
        }
        #pragma unroll
        for (int kk = 0; kk < 8; kk += 2)           // scanB hides under drain
            scan2(s_cb, s_cb2, k0 + it * 8 + kk, zB, enc2pB, bestB0, bestB1, biB0, biB1);
    }
    *(float2*)(&s_sd[sidx][t2]) = make_float2(bestB0, bestB1);
    *(int2*)  (&s_si[sidx][t2]) = make_int2(biB0, biB1);
    __syncthreads();   // (5) sdB/siB visible (stores drained; scanB already ran)

    // ---- combine B ----
    int gbiB;
    {
        float g = s_sd[0][lane];
        gbiB = s_si[0][lane];
        #pragma unroll
        for (int s2 = 1; s2 < 16; ++s2) {
            float d2 = s_sd[s2][lane];
            int   i2 = s_si[s2][lane];
            if (d2 < g) { g = d2; gbiB = i2; }
        }
    }
    float4 qBa = ((const float4*)s_cb)[2 * gbiB];
    float4 qBb = ((const float4*)s_cb)[2 * gbiB + 1];

    // ---- commit B + idx B (wave 0); total commit = clA + clB ----
    if (wu == 0) {
        float clB = 0.f, f;
        f = s_zeB[0*64+lane]-qBa.x; clB = fmaf(f,f,clB);
        f = s_zeB[1*64+lane]-qBa.y; clB = fmaf(f,f,clB);
        f = s_zeB[2*64+lane]-qBa.z; clB = fmaf(f,f,clB);
        f = s_zeB[3*64+lane]-qBa.w; clB = fmaf(f,f,clB);
        f = s_zeB[4*64+lane]-qBb.x; clB = fmaf(f,f,clB);
        f = s_zeB[5*64+lane]-qBb.y; clB = fmaf(f,f,clB);
        f = s_zeB[6*64+lane]-qBb.z; clB = fmaf(f,f,clB);
        f = s_zeB[7*64+lane]-qBb.w; clB = fmaf(f,f,clB);
        #pragma unroll
        for (int off = 32; off > 0; off >>= 1) clB += __shfl_xor(clB, off, 64);
        if (lane == 0) ws_commit[blk] = clA + clB;
        out[(size_t)NB * DIN * TT + NB + (size_t)b * TT + t0 + 64 + lane] = (float)gbiB;
    }

    // ---- out-proj B ----
    float* outpB = outpA + 64;
    #pragma unroll 4
    for (int oo = 0; oo < 64; ++oo) {
        int o = d0 + oo;
        const float* wo = w_out + o * DCB;   // uniform -> s_load
        float a = fmaf(wo[0], qBa.x, fmaf(wo[1], qBa.y, fmaf(wo[2], qBa.z, fmaf(wo[3], qBa.w,
                  fmaf(wo[4], qBb.x, fmaf(wo[5], qBb.y, fmaf(wo[6], qBb.z, wo[7] * qBb.w)))))));
        outpB[(size_t)o * TT] = a + out_b[o];
    }
}

__global__ __launch_bounds__(64) void vq_commit(
    const float* __restrict__ ws_commit, float* __restrict__ out)
{
    int b    = blockIdx.x;
    int lane = threadIdx.x;
    float s = (lane < 32) ? ws_commit[b * 32 + lane] : 0.f;
    #pragma unroll
    for (int off = 32; off > 0; off >>= 1) s += __shfl_xor(s, off, 64);
    if (lane == 0)
        out[(size_t)NB * DIN * TT + b] = s * (1.0f / (DCB * TT));
}

extern "C" void kernel_launch(void* const* d_in, const int* in_sizes, int n_in,
                              void* d_out, int out_size, void* d_ws, size_t ws_size,
                              hipStream_t stream) {
    const float* z     = (const float*)d_in[0];
    const float* in_v  = (const float*)d_in[1];
    const float* in_g  = (const float*)d_in[2];
    const float* in_b  = (const float*)d_in[3];
    const float* out_v = (const float*)d_in[4];
    const float* out_g = (const float*)d_in[5];
    const float* out_b = (const float*)d_in[6];
    const float* cb    = (const float*)d_in[7];

    float* ws  = (float*)d_ws;
    float* out = (float*)d_out;

    vq_setup<<<1, 512, 0, stream>>>(in_v, in_g, out_v, out_g, cb, ws);
    vq_main<<<512, 512, 0, stream>>>(z, in_b, out_b, cb, ws, ws + 9216, out);
    vq_commit<<<NB, 64, 0, stream>>>(ws + 9216, out);
}

// Round 17
// 67.247 us; speedup vs baseline: 1.0783x; 1.0783x over previous
//
#include <hip/hip_runtime.h>
#include <math.h>

#define NB 16
#define DIN 512
#define TT 4096
#define DCB 8
#define KC 1024
#define NW 8            // waves per block
#define TC 128          // t-chunk per block

typedef float v2f __attribute__((ext_vector_type(2)));

// v_pk_*_f32 with op_sel word-broadcast of src1 (wave-uniform cb operand).
#define PK_MUL_LO(d, a, b)    asm("v_pk_mul_f32 %0, %1, %2 op_sel_hi:[1,0]"       : "=v"(d) : "v"(a), "v"(b))
#define PK_MUL_HI(d, a, b)    asm("v_pk_mul_f32 %0, %1, %2 op_sel:[0,1]"          : "=v"(d) : "v"(a), "v"(b))
#define PK_FMA_LO(d, a, b, c) asm("v_pk_fma_f32 %0, %1, %2, %3 op_sel_hi:[1,0,1]" : "=v"(d) : "v"(a), "v"(b), "v"(c))
#define PK_FMA_HI(d, a, b, c) asm("v_pk_fma_f32 %0, %1, %2, %3 op_sel:[0,1,0]"    : "=v"(d) : "v"(a), "v"(b), "v"(c))
#define PK_FMA(d, a, b, c)    asm("v_pk_fma_f32 %0, %1, %2, %3"                   : "=v"(d) : "v"(a), "v"(b), "v"(c))
#define PK_ADD_LO(d, a, b)    asm("v_pk_add_f32 %0, %1, %2 op_sel_hi:[1,0]"       : "=v"(d) : "v"(a), "v"(b))
#define PK_ADD_HI(d, a, b)    asm("v_pk_add_f32 %0, %1, %2 op_sel:[0,1]"          : "=v"(d) : "v"(a), "v"(b))

// ws layout (floats):
// [0,4096)      w_inT[d][c]   (transposed)
// [4096,8192)   w_out[o][c]
// [8192,9216)   cb2[k]
// [9216,9728)   per-block commit partials (512)

__global__ __launch_bounds__(512) void vq_setup(
    const float* __restrict__ in_v, const float* __restrict__ in_g,
    const float* __restrict__ out_v, const float* __restrict__ out_g,
    const float* __restrict__ cb, float* __restrict__ ws)
{
    int tid = threadIdx.x;
    float* w_inT = ws;
    float* w_out = ws + 4096;
    float* cb2   = ws + 8192;

    {   // w_in: 8 rows of 512; one wave per row
        int c    = tid >> 6;
        int lane = tid & 63;
        const float* v = in_v + c * DIN;
        float s = 0.f;
        #pragma unroll
        for (int i = 0; i < DIN; i += 64) {
            float x = v[i + lane];
            s += x * x;
        }
        #pragma unroll
        for (int off = 32; off > 0; off >>= 1) s += __shfl_xor(s, off, 64);
        float sq = sqrtf(s);
        float g  = in_g[c];
        #pragma unroll
        for (int i = 0; i < DIN; i += 64) {
            int d = i + lane;
            w_inT[d * DCB + c] = (g * v[d]) / sq;
        }
    }
    {   // w_out: 512 rows of 8
        int o = tid;
        const float* v = out_v + o * DCB;
        float s = 0.f;
        #pragma unroll
        for (int c = 0; c < DCB; ++c) s += v[c] * v[c];
        float sq = sqrtf(s);
        float g  = out_g[o];
        #pragma unroll
        for (int c = 0; c < DCB; ++c) w_out[o * DCB + c] = (g * v[c]) / sq;
    }
    for (int k = tid; k < KC; k += 512) {
        const float* r = cb + k * DCB;
        float s = 0.f;
        #pragma unroll
        for (int c = 0; c < DCB; ++c) s += r[c] * r[c];
        cb2[k] = s;
    }
}

// Fused main (r14: r13 structure; scan uses packed fp32, bit-identical order).
__global__ __launch_bounds__(512, 4) void vq_main(
    const float* __restrict__ z, const float* __restrict__ in_b,
    const float* __restrict__ out_b, const float* __restrict__ cb,
    const float* __restrict__ ws, float* __restrict__ ws_commit,
    float* __restrict__ out)
{
    __shared__ float s_buf[KC * DCB];   // 32 KB overlay: red [w][c][t] -> cb [k][c]
    __shared__ float s_ze[DCB * TC];    // 4 KB  [c][t] reduced ze
    __shared__ float s_cb2[KC];         // 4 KB
    __shared__ float s_sd[16][TC];      // 8 KB
    __shared__ int   s_si[16][TC];      // 8 KB   total 56 KB

    const float* w_inT = ws;
    const float* w_out = ws + 4096;

    int tid  = threadIdx.x;
    int w    = tid >> 6;
    int wu   = __builtin_amdgcn_readfirstlane(w);
    int lane = tid & 63;
    int blk  = blockIdx.x;               // 0..511
    int b    = blk >> 5;
    int t0   = (blk & 31) * TC;
    int tl   = 2 * lane;

    // cb2 -> LDS at top
    if (tid < 256) {
        float4 q = ((const float4*)(ws + 8192))[tid];
        ((float4*)s_cb2)[tid] = q;
    }

    const float* zp = z + (size_t)b * DIN * TT + t0 + tl;

    // ---- in-projection over d in [wu*64, wu*64+64) ----
    float ze0[DCB], ze1[DCB];
    #pragma unroll
    for (int c = 0; c < DCB; ++c) { ze0[c] = 0.f; ze1[c] = 0.f; }

    int d0 = wu * 64;
    for (int db = 0; db < 64; db += 8) {
        float2 v[8];
        #pragma unroll
        for (int j = 0; j < 8; ++j)
            v[j] = *(const float2*)(zp + (size_t)(d0 + db + j) * TT);
        #pragma unroll
        for (int j = 0; j < 8; ++j) {
            const float* wi = w_inT + (d0 + db + j) * DCB;  // uniform -> s_load
            #pragma unroll
            for (int c = 0; c < DCB; ++c) {
                ze0[c] = fmaf(wi[c], v[j].x, ze0[c]);
                ze1[c] = fmaf(wi[c], v[j].y, ze1[c]);
            }
        }
    }

    // ---- write red partials [w][c][t] ----
    {
        float* redw = s_buf + w * (DCB * TC);
        #pragma unroll
        for (int c = 0; c < DCB; ++c)
            *(float2*)(redw + c * TC + tl) = make_float2(ze0[c], ze1[c]);
    }

    // ---- prefetch cb into regs (returns during reduce) ----
    float4 p0 = ((const float4*)cb)[tid];
    float4 p1 = ((const float4*)cb)[512 + tid];
    float4 p2 = ((const float4*)cb)[1024 + tid];
    float4 p3 = ((const float4*)cb)[1536 + tid];

    __syncthreads();   // (1) red visible

    // ---- distributed reduce: this thread owns (c=w, t=tl..tl+1) ----
    {
        float sa = 0.f, sb = 0.f;
        #pragma unroll
        for (int w2 = 0; w2 < NW; ++w2) {
            float2 r = *(const float2*)(s_buf + w2 * (DCB * TC) + w * TC + tl);
            sa += r.x; sb += r.y;
        }
        float bias = in_b[w];              // uniform -> s_load
        *(float2*)(s_ze + w * TC + tl) = make_float2(sa + bias, sb + bias);
    }
    __syncthreads();   // (2) red reads done -> s_buf reusable

    // ---- overwrite s_buf with codebook ----
    ((float4*)s_buf)[tid]        = p0;
    ((float4*)s_buf)[512 + tid]  = p1;
    ((float4*)s_buf)[1024 + tid] = p2;
    ((float4*)s_buf)[1536 + tid] = p3;
    __syncthreads();   // (3) cb + s_ze visible

    // ---- scan: lane -> 4 t's (2 packed t-pairs), 64-k slice ----
    {
        int h  = lane >> 5;
        int t4 = 4 * (lane & 31);
        int s  = 2 * w + h;                // slice index, k ascending with s
        int k0 = 64 * s;

        v2f zp2[DCB][2];
        float zr[DCB][4];
        #pragma unroll
        for (int c = 0; c < DCB; ++c) {
            float4 v = *(const float4*)(s_ze + c * TC + t4);
            zr[c][0] = v.x; zr[c][1] = v.y; zr[c][2] = v.z; zr[c][3] = v.w;
            zp2[c][0] = (v2f){v.x, v.y};
            zp2[c][1] = (v2f){v.z, v.w};
        }
        float enc2[4];
        #pragma unroll
        for (int j = 0; j < 4; ++j) {
            float e = 0.f;
            #pragma unroll
            for (int c = 0; c < DCB; ++c) e += zr[c][j] * zr[c][j];
            enc2[j] = e;
        }
        v2f enc2p[2] = { (v2f){enc2[0], enc2[1]}, (v2f){enc2[2], enc2[3]} };
        v2f neg2 = (v2f){-2.0f, -2.0f};

        float best[4] = {3.4e38f, 3.4e38f, 3.4e38f, 3.4e38f};
        int   bi[4]   = {0, 0, 0, 0};

        #pragma unroll 2
        for (int kk = 0; kk < 64; kk += 2) {
            v2f c2q = *(const v2f*)(s_cb2 + k0 + kk);   // cb2 for k, k+1
            #pragma unroll
            for (int u = 0; u < 2; ++u) {
                int k = k0 + kk + u;
                float4 r0 = ((const float4*)s_buf)[2 * k];
                float4 r1 = ((const float4*)s_buf)[2 * k + 1];
                v2f cbA = (v2f){r0.x, r0.y};
                v2f cbB = (v2f){r0.z, r0.w};
                v2f cbC = (v2f){r1.x, r1.y};
                v2f cbD = (v2f){r1.z, r1.w};
                #pragma unroll
                for (int p = 0; p < 2; ++p) {
                    v2f acc;
                    PK_MUL_HI(acc, zp2[7][p], cbD);
                    PK_FMA_LO(acc, zp2[6][p], cbD, acc);
                    PK_FMA_HI(acc, zp2[5][p], cbC, acc);
                    PK_FMA_LO(acc, zp2[4][p], cbC, acc);
                    PK_FMA_HI(acc, zp2[3][p], cbB, acc);
                    PK_FMA_LO(acc, zp2[2][p], cbB, acc);
                    PK_FMA_HI(acc, zp2[1][p], cbA, acc);
                    PK_FMA_LO(acc, zp2[0][p], cbA, acc);
                    v2f dk2;
                    PK_FMA(dk2, acc, neg2, enc2p[p]);
                    if (u == 0) { PK_ADD_LO(dk2, dk2, c2q); }
                    else        { PK_ADD_HI(dk2, dk2, c2q); }
                    float dkx = dk2.x, dky = dk2.y;
                    if (dkx < best[2*p])     { best[2*p]     = dkx; bi[2*p]     = k; }
                    if (dky < best[2*p + 1]) { best[2*p + 1] = dky; bi[2*p + 1] = k; }
                }
            }
        }
        *(float4*)(&s_sd[s][t4]) = make_float4(best[0], best[1], best[2], best[3]);
        *(int4*)  (&s_si[s][t4]) = make_int4(bi[0], bi[1], bi[2], bi[3]);
    }
    __syncthreads();   // (4) sd/si visible

    // ---- ordered combine over 16 slices (strict <, k-ascending) ----
    float g0 = s_sd[0][tl], g1 = s_sd[0][tl + 1];
    int  gi0 = s_si[0][tl], gi1 = s_si[0][tl + 1];
    #pragma unroll
    for (int s2 = 1; s2 < 16; ++s2) {
        float d0_ = s_sd[s2][tl],  d1_ = s_sd[s2][tl + 1];
        int   i0_ = s_si[s2][tl],  i1_ = s_si[s2][tl + 1];
        if (d0_ < g0) { g0 = d0_; gi0 = i0_; }
        if (d1_ < g1) { g1 = d1_; gi1 = i1_; }
    }

    // ---- z_q rows from LDS ----
    float4 q0a = ((const float4*)s_buf)[2 * gi0], q0b = ((const float4*)s_buf)[2 * gi0 + 1];
    float4 q1a = ((const float4*)s_buf)[2 * gi1], q1b = ((const float4*)s_buf)[2 * gi1 + 1];

    // ---- commit loss + indices: wave 0 ONLY ----
    if (wu == 0) {
        float zeA[DCB], zeB[DCB];
        #pragma unroll
        for (int c = 0; c < DCB; ++c) {
            float2 zz = *(const float2*)(s_ze + c * TC + tl);
            zeA[c] = zz.x; zeB[c] = zz.y;
        }
        float cl = 0.f, f;
        f = zeA[0]-q0a.x; cl = fmaf(f,f,cl);  f = zeB[0]-q1a.x; cl = fmaf(f,f,cl);
        f = zeA[1]-q0a.y; cl = fmaf(f,f,cl);  f = zeB[1]-q1a.y; cl = fmaf(f,f,cl);
        f = zeA[2]-q0a.z; cl = fmaf(f,f,cl);  f = zeB[2]-q1a.z; cl = fmaf(f,f,cl);
        f = zeA[3]-q0a.w; cl = fmaf(f,f,cl);  f = zeB[3]-q1a.w; cl = fmaf(f,f,cl);
        f = zeA[4]-q0b.x; cl = fmaf(f,f,cl);  f = zeB[4]-q1b.x; cl = fmaf(f,f,cl);
        f = zeA[5]-q0b.y; cl = fmaf(f,f,cl);  f = zeB[5]-q1b.y; cl = fmaf(f,f,cl);
        f = zeA[6]-q0b.z; cl = fmaf(f,f,cl);  f = zeB[6]-q1b.z; cl = fmaf(f,f,cl);
        f = zeA[7]-q0b.w; cl = fmaf(f,f,cl);  f = zeB[7]-q1b.w; cl = fmaf(f,f,cl);
        #pragma unroll
        for (int off = 32; off > 0; off >>= 1) cl += __shfl_xor(cl, off, 64);
        if (lane == 0) ws_commit[blk] = cl;
        float2 iv = make_float2((float)gi0, (float)gi1);
        *(float2*)(out + (size_t)NB * DIN * TT + NB + (size_t)b * TT + t0 + tl) = iv;
    }

    // ---- out-projection over o in [wu*64, wu*64+64) ----
    float* outp = out + (size_t)b * DIN * TT + t0 + tl;
    int o0 = wu * 64;
    #pragma unroll 4
    for (int oo = 0; oo < 64; ++oo) {
        int o = o0 + oo;
        const float* wo = w_out + o * DCB;   // uniform -> s_load_dwordx8
        float obias = out_b[o];              // uniform -> s_load
        float a0 = fmaf(wo[0], q0a.x, fmaf(wo[1], q0a.y, fmaf(wo[2], q0a.z, fmaf(wo[3], q0a.w,
                   fmaf(wo[4], q0b.x, fmaf(wo[5], q0b.y, fmaf(wo[6], q0b.z, wo[7] * q0b.w)))))));
        float a1 = fmaf(wo[0], q1a.x, fmaf(wo[1], q1a.y, fmaf(wo[2], q1a.z, fmaf(wo[3], q1a.w,
                   fmaf(wo[4], q1b.x, fmaf(wo[5], q1b.y, fmaf(wo[6], q1b.z, wo[7] * q1b.w)))))));
        *(float2*)(outp + (size_t)o * TT) = make_float2(a0 + obias, a1 + obias);
    }
}

__global__ __launch_bounds__(64) void vq_commit(
    const float* __restrict__ ws_commit, float* __restrict__ out)
{
    int b    = blockIdx.x;
    int lane = threadIdx.x;
    float s = (lane < 32) ? ws_commit[b * 32 + lane] : 0.f;
    #pragma unroll
    for (int off = 32; off > 0; off >>= 1) s += __shfl_xor(s, off, 64);
    if (lane == 0)
        out[(size_t)NB * DIN * TT + b] = s * (1.0f / (DCB * TT));
}

extern "C" void kernel_launch(void* const* d_in, const int* in_sizes, int n_in,
                              void* d_out, int out_size, void* d_ws, size_t ws_size,
                              hipStream_t stream) {
    const float* z     = (const float*)d_in[0];
    const float* in_v  = (const float*)d_in[1];
    const float* in_g  = (const float*)d_in[2];
    const float* in_b  = (const float*)d_in[3];
    const float* out_v = (const float*)d_in[4];
    const float* out_g = (const float*)d_in[5];
    const float* out_b = (const float*)d_in[6];
    const float* cb    = (const float*)d_in[7];

    float* ws  = (float*)d_ws;
    float* out = (float*)d_out;

    vq_setup<<<1, 512, 0, stream>>>(in_v, in_g, out_v, out_g, cb, ws);
    vq_main<<<512, 512, 0, stream>>>(z, in_b, out_b, cb, ws, ws + 9216, out);
    vq_commit<<<NB, 64, 0, stream>>>(ws + 9216, out);
}